// Round 6
// baseline (223.497 us; speedup 1.0000x reference)
//
#include <hip/hip_runtime.h>

typedef float f4 __attribute__((ext_vector_type(4)));
typedef __attribute__((ext_vector_type(4))) float f32x4;
typedef __attribute__((ext_vector_type(8))) short bf8;

__device__ __forceinline__ float bf2f(unsigned hu16) {
    union { unsigned u; float f; } v; v.u = hu16 << 16;
    return v.f;
}
// truncation split: hi = top 16 bits, lo = trunc(v - hi). lo captures hi's
// truncation residual, so net precision ~2^-16 relative — RNE not needed.
__device__ __forceinline__ void split2t(float v, ushort& hi, ushort& lo) {
    union { float f; unsigned u; } a; a.f = v;
    unsigned hu = a.u & 0xFFFF0000u;
    hi = (ushort)(hu >> 16);
    union { unsigned u; float f; } hv; hv.u = hu;
    union { float f; unsigned u; } lres; lres.f = v - hv.f;
    lo = (ushort)(lres.u >> 16);
}
__device__ __forceinline__ ushort ftrunc_bf(float f) {
    union { float f; unsigned u; } v; v.f = f;
    return (ushort)(v.u >> 16);
}

__global__ __launch_bounds__(256, 3)
void avif_mfma6(const float* __restrict__ x, const float* __restrict__ twm,
                const float* __restrict__ w1, const float* __restrict__ b1,
                const float* __restrict__ w2, const float* __restrict__ b2,
                float* __restrict__ out)
{
    // XOR-swizzled planes, granule = 8 ushorts (16B):
    // element (px, c) -> row px, ushort idx = swz(px, c>>3)*8 + (c&7)
    // swz(px, g) = g ^ (px&7) ^ (((px>>3)&1)<<2)
    __shared__ ushort ysh[128][64];   // Y hi
    __shared__ ushort ysl[128][64];   // Y lo
    __shared__ ushort hsh[128][64];   // H hi (48 KB -> 3 blocks/CU)

    const int t = threadIdx.x;
    const int bid = blockIdx.x;
    // XCD-friendly decode
    const int b3 = (bid >> 3) & 1;
    const int u  = ((bid >> 4) << 3) | (bid & 7);
    const int wt = ((u & 15) << 1) | b3;   // 0..31
    const int hb = (u >> 4) & 63;          // 0..63
    const int b  = u >> 10;                // 0..3

    const int wv   = t >> 6;
    const int lane = t & 63;
    const int li   = lane & 15;
    const int lg   = lane >> 4;
    const int l7   = li & 7;
    const int lb3  = (li >> 3) << 2;       // row-bit-3 swizzle term

    // ---- phase 1: lane pair shares one (c,blk); q-partitioned (each lane
    // owns 4 Y COLUMNS q = 4*h2..4*h2+3, all 8 rows). M is [8][4]. ----
    {
        const int pid = t >> 1;          // 0..127
        const int h2  = t & 1;
        const int c   = pid & 63, blk = pid >> 6;
        const int Q0  = 4 * h2;
        const float* xB = x + ((size_t)(b * 64 + c) * 512 + hb * 8) * 512
                            + wt * 16 + blk * 8;
        const float* tB = twm + c * 64;

        float M[8][4];
        {
            f4 Ph[8];
#pragma unroll
            for (int i = 0; i < 8; ++i) Ph[i] = *(const f4*)(xB + i * 512);
#pragma unroll
            for (int qq = 0; qq < 4; ++qq) {
                f4 Th = *(const f4*)(tB + (Q0 + qq) * 8);
#pragma unroll
                for (int i = 0; i < 8; ++i) {
                    float s = Ph[i][0] * Th[0];
                    s = fmaf(Ph[i][1], Th[1], s);
                    s = fmaf(Ph[i][2], Th[2], s);
                    s = fmaf(Ph[i][3], Th[3], s);
                    M[i][qq] = s;
                }
            }
#pragma unroll
            for (int i = 0; i < 8; ++i) Ph[i] = *(const f4*)(xB + i * 512 + 4);
#pragma unroll
            for (int qq = 0; qq < 4; ++qq) {
                f4 Th = *(const f4*)(tB + (Q0 + qq) * 8 + 4);
#pragma unroll
                for (int i = 0; i < 8; ++i) {
                    float s = M[i][qq];
                    s = fmaf(Ph[i][0], Th[0], s);
                    s = fmaf(Ph[i][1], Th[1], s);
                    s = fmaf(Ph[i][2], Th[2], s);
                    s = fmaf(Ph[i][3], Th[3], s);
                    M[i][qq] = s;
                }
            }
        }
        const int cg = c >> 3, c7 = c & 7;
#pragma unroll
        for (int p = 0; p < 8; ++p) {
            f4 a = *(const f4*)(tB + p * 8);
            f4 d = *(const f4*)(tB + p * 8 + 4);
            const int px0 = p * 16 + blk * 8;
#pragma unroll
            for (int qq = 0; qq < 4; ++qq) {
                const int q = Q0 + qq;
                float s = a[0] * M[0][qq];
                s = fmaf(a[1], M[1][qq], s);
                s = fmaf(a[2], M[2][qq], s);
                s = fmaf(a[3], M[3][qq], s);
                s = fmaf(d[0], M[4][qq], s);
                s = fmaf(d[1], M[5][qq], s);
                s = fmaf(d[2], M[6][qq], s);
                s = fmaf(d[3], M[7][qq], s);
                ushort hi, lo; split2t(s, hi, lo);
                const int idx = ((cg ^ q ^ (blk << 2)) << 3) | c7;  // px&7==q, px bit3==blk
                ysh[px0 + q][idx] = hi;
                ysl[px0 + q][idx] = lo;
            }
        }
    }

    // ---- W fragments (hi+lo) in registers ----
    bf8 w1h[2], w1l[2], w2h[2], w2l[2];
    {
        const float* p1 = w1 + (16 * wv + li) * 64 + lg * 8;
        const float* p2 = w2 + (16 * wv + li) * 64 + lg * 8;
#pragma unroll
        for (int kk = 0; kk < 2; ++kk) {
            f4 a = *(const f4*)(p1 + kk * 32);
            f4 d = *(const f4*)(p1 + kk * 32 + 4);
            bf8 fh, fl; ushort hi, lo;
#pragma unroll
            for (int q = 0; q < 4; ++q) {
                split2t(a[q], hi, lo); fh[q] = (short)hi; fl[q] = (short)lo;
                split2t(d[q], hi, lo); fh[4 + q] = (short)hi; fl[4 + q] = (short)lo;
            }
            w1h[kk] = fh; w1l[kk] = fl;
            a = *(const f4*)(p2 + kk * 32);
            d = *(const f4*)(p2 + kk * 32 + 4);
#pragma unroll
            for (int q = 0; q < 4; ++q) {
                split2t(a[q], hi, lo); fh[q] = (short)hi; fl[q] = (short)lo;
                split2t(d[q], hi, lo); fh[4 + q] = (short)hi; fl[4 + q] = (short)lo;
            }
            w2h[kk] = fh; w2l[kk] = fl;
        }
    }
    const int o0 = 16 * wv + 4 * lg;
    const f4 b1v = *(const f4*)(b1 + o0);
    const float b2s = b2[16 * wv + li];
    const int sg0 = ((lg       ^ l7 ^ lb3) << 3);
    const int sg1 = (((4 + lg) ^ l7 ^ lb3) << 3);
    const int go  = o0 >> 3, co = 4 * (lg & 1);

    __syncthreads();

    // ---- GEMM1: H = relu(W1 * Y + b1), split x split (A=W1, B=Y) ----
    f32x4 acc[8];
#pragma unroll
    for (int j = 0; j < 8; ++j) acc[j] = (f32x4){0.f, 0.f, 0.f, 0.f};
#pragma unroll
    for (int j = 0; j < 8; ++j) {
        const int row = 16 * j + li;
        bf8 bh0 = *(const bf8*)&ysh[row][sg0];
        bf8 bl0 = *(const bf8*)&ysl[row][sg0];
        bf8 bh1 = *(const bf8*)&ysh[row][sg1];
        bf8 bl1 = *(const bf8*)&ysl[row][sg1];
        acc[j] = __builtin_amdgcn_mfma_f32_16x16x32_bf16(w1h[0], bh0, acc[j], 0, 0, 0);
        acc[j] = __builtin_amdgcn_mfma_f32_16x16x32_bf16(w1h[0], bl0, acc[j], 0, 0, 0);
        acc[j] = __builtin_amdgcn_mfma_f32_16x16x32_bf16(w1l[0], bh0, acc[j], 0, 0, 0);
        acc[j] = __builtin_amdgcn_mfma_f32_16x16x32_bf16(w1h[1], bh1, acc[j], 0, 0, 0);
        acc[j] = __builtin_amdgcn_mfma_f32_16x16x32_bf16(w1h[1], bl1, acc[j], 0, 0, 0);
        acc[j] = __builtin_amdgcn_mfma_f32_16x16x32_bf16(w1l[1], bh1, acc[j], 0, 0, 0);
    }
#pragma unroll
    for (int j = 0; j < 8; ++j) {
        const int px = 16 * j + li;
        const int idx = ((go ^ l7 ^ lb3) << 3) + co;
        unsigned h0 = ftrunc_bf(fmaxf(acc[j][0] + b1v[0], 0.f));
        unsigned h1 = ftrunc_bf(fmaxf(acc[j][1] + b1v[1], 0.f));
        unsigned h2 = ftrunc_bf(fmaxf(acc[j][2] + b1v[2], 0.f));
        unsigned h3 = ftrunc_bf(fmaxf(acc[j][3] + b1v[3], 0.f));
        *(unsigned*)&hsh[px][idx]     = h0 | (h1 << 16);
        *(unsigned*)&hsh[px][idx + 2] = h2 | (h3 << 16);
    }
    __syncthreads();

    // ---- GEMM2 SWAPPED (A=H-frag, B=W2-frag): D[px][channel] ----
    // lane: channel = 16*wv+li, px rows = 16*j + 4*lg + r  -> f4 stores
#pragma unroll
    for (int j = 0; j < 8; ++j) acc[j] = (f32x4){0.f, 0.f, 0.f, 0.f};
#pragma unroll
    for (int j = 0; j < 8; ++j) {
        const int row = 16 * j + li;
        bf8 ah0 = *(const bf8*)&hsh[row][sg0];
        bf8 ah1 = *(const bf8*)&hsh[row][sg1];
        acc[j] = __builtin_amdgcn_mfma_f32_16x16x32_bf16(ah0, w2h[0], acc[j], 0, 0, 0);
        acc[j] = __builtin_amdgcn_mfma_f32_16x16x32_bf16(ah0, w2l[0], acc[j], 0, 0, 0);
        acc[j] = __builtin_amdgcn_mfma_f32_16x16x32_bf16(ah1, w2h[1], acc[j], 0, 0, 0);
        acc[j] = __builtin_amdgcn_mfma_f32_16x16x32_bf16(ah1, w2l[1], acc[j], 0, 0, 0);
    }
    const int ch = 16 * wv + li;
    const int cgE = ch >> 3, c7E = li & 7;
    float* oB = out + ((size_t)(b * 64) + ch) * 262144
                + (size_t)(hb * 8) * 512 + wt * 16 + 4 * lg;
#pragma unroll
    for (int j = 0; j < 8; ++j) {
        f4 r;
#pragma unroll
        for (int r4 = 0; r4 < 4; ++r4) {
            const int pc = 4 * lg + r4;                 // px within row-tile
            const int px = 16 * j + pc;
            const int idx = ((cgE ^ (pc & 7) ^ (((pc >> 3) & 1) << 2)) << 3) | c7E;
            float yv = bf2f((unsigned)ysh[px][idx]) + bf2f((unsigned)ysl[px][idx]);
            float z = acc[j][r4] + b2s;
            float g = __builtin_amdgcn_rcpf(1.f + __expf(-z));
            r[r4] = yv * g;
        }
        *(f4*)(oB + (size_t)j * 512) = r;
    }
}

extern "C" void kernel_launch(void* const* d_in, const int* in_sizes, int n_in,
                              void* d_out, int out_size, void* d_ws, size_t ws_size,
                              hipStream_t stream) {
    (void)in_sizes; (void)n_in; (void)out_size; (void)d_ws; (void)ws_size;
    const float* x   = (const float*)d_in[0];
    const float* twm = (const float*)d_in[1];
    const float* w1  = (const float*)d_in[2];
    const float* b1  = (const float*)d_in[3];
    const float* w2  = (const float*)d_in[4];
    const float* b2  = (const float*)d_in[5];
    float* out = (float*)d_out;

    avif_mfma6<<<dim3(4 * 64 * 32), dim3(256), 0, stream>>>(x, twm, w1, b1, w2, b2, out);
}